// Round 11
// baseline (41.807 us; speedup 1.0000x reference)
//
#include <hip/hip_runtime.h>
#include <hip/hip_bf16.h>

// Problem constants (match reference setup_inputs)
#define BB 64
#define SS 512
#define DD 1024
#define VV 64
#define NSEG (BB * SS)        // 32768
#define THREADS 512
#define WPB (THREADS / 64)    // 8 waves per block
#define SEGS_PER_WAVE 2
#define GRID (NSEG / (WPB * SEGS_PER_WAVE))   // 2048 blocks

typedef float f32x4 __attribute__((ext_vector_type(4)));

// ---------- Pass A: segment start offsets from sorted segment_ids ----------
__global__ __launch_bounds__(256) void fill_bounds_kernel(
    const int* __restrict__ seg_ids,
    int* __restrict__ seg_start,
    int T)
{
    int t = blockIdx.x * blockDim.x + threadIdx.x;
    if (t >= T) return;
    int cur  = seg_ids[t];
    int prev = (t == 0) ? -1 : seg_ids[t - 1];
    for (int s = prev + 1; s <= cur; ++s) seg_start[s] = t;
    if (t == T - 1) {
        for (int s = cur + 1; s <= NSEG; ++s) seg_start[s] = T;
    }
}

// ---------- Pass B: two segments per wave, fused gather loop ----------
// Per iteration the A-chain and B-chain loads are independent -> 2x memory-level
// parallelism vs R10 (8 concurrent 1KB gathers per wave instead of 4). Guards
// (i<c0 / i<c1) are wave-uniform -> scalar branches, no divergence. 8KB of
// contiguous NT stores per wave at the end.
__global__ __launch_bounds__(THREADS) void seg_mean_2s_kernel(
    const int* __restrict__ tokens,
    const int* __restrict__ seg_start,  // [NSEG+1]
    const float* __restrict__ emb,      // [V, D]
    const float* __restrict__ pos,      // [S, D]
    float* __restrict__ out)            // [B*S, D]
{
    const int wave = threadIdx.x >> 6;
    const int lane = threadIdx.x & 63;
    const int s0   = (blockIdx.x * WPB + wave) * 2;   // even
    const int d0   = lane * 4;

    const int lo0 = seg_start[s0];
    const int mid = seg_start[s0 + 1];
    const int hi1 = seg_start[s0 + 2];
    const int c0 = mid - lo0;
    const int c1 = hi1 - mid;
    const int cmax = (c0 > c1) ? c0 : c1;

    f32x4 a0 = (f32x4)(0.f), a1 = (f32x4)(0.f), a2 = (f32x4)(0.f), a3 = (f32x4)(0.f);
    f32x4 b0 = (f32x4)(0.f), b1 = (f32x4)(0.f), b2 = (f32x4)(0.f), b3 = (f32x4)(0.f);

    for (int i = 0; i < cmax; ++i) {
        if (i < c0) {
            const int tok = tokens[lo0 + i];             // uniform
            const float* e = emb + (size_t)tok * DD + d0;
            a0 += *reinterpret_cast<const f32x4*>(e);
            a1 += *reinterpret_cast<const f32x4*>(e + 256);
            a2 += *reinterpret_cast<const f32x4*>(e + 512);
            a3 += *reinterpret_cast<const f32x4*>(e + 768);
        }
        if (i < c1) {
            const int tok = tokens[mid + i];             // uniform
            const float* e = emb + (size_t)tok * DD + d0;
            b0 += *reinterpret_cast<const f32x4*>(e);
            b1 += *reinterpret_cast<const f32x4*>(e + 256);
            b2 += *reinterpret_cast<const f32x4*>(e + 512);
            b3 += *reinterpret_cast<const f32x4*>(e + 768);
        }
    }

    const float invA = (c0 > 0) ? (1.0f / (float)c0) : 0.0f;
    const float invB = (c1 > 0) ? (1.0f / (float)c1) : 0.0f;

    // s0 is even so (s0 % 512) <= 510: pos row for s0+1 is always prow + DD.
    const float* prow = pos + (size_t)(s0 & (SS - 1)) * DD + d0;
    float* orow = out + (size_t)s0 * DD + d0;

    f32x4 o;
    o = a0 * invA + *reinterpret_cast<const f32x4*>(prow);
    __builtin_nontemporal_store(o, reinterpret_cast<f32x4*>(orow));
    o = a1 * invA + *reinterpret_cast<const f32x4*>(prow + 256);
    __builtin_nontemporal_store(o, reinterpret_cast<f32x4*>(orow + 256));
    o = a2 * invA + *reinterpret_cast<const f32x4*>(prow + 512);
    __builtin_nontemporal_store(o, reinterpret_cast<f32x4*>(orow + 512));
    o = a3 * invA + *reinterpret_cast<const f32x4*>(prow + 768);
    __builtin_nontemporal_store(o, reinterpret_cast<f32x4*>(orow + 768));

    o = b0 * invB + *reinterpret_cast<const f32x4*>(prow + DD);
    __builtin_nontemporal_store(o, reinterpret_cast<f32x4*>(orow + DD));
    o = b1 * invB + *reinterpret_cast<const f32x4*>(prow + DD + 256);
    __builtin_nontemporal_store(o, reinterpret_cast<f32x4*>(orow + DD + 256));
    o = b2 * invB + *reinterpret_cast<const f32x4*>(prow + DD + 512);
    __builtin_nontemporal_store(o, reinterpret_cast<f32x4*>(orow + DD + 512));
    o = b3 * invB + *reinterpret_cast<const f32x4*>(prow + DD + 768);
    __builtin_nontemporal_store(o, reinterpret_cast<f32x4*>(orow + DD + 768));
}

// ---------- Fallback (ws too small): binary-search kernel ----------
__device__ __forceinline__ int lower_bound_dev(const int* __restrict__ a, int n, int key) {
    int lo = 0, hi = n;
    while (lo < hi) {
        int mid = (lo + hi) >> 1;
        if (a[mid] < key) lo = mid + 1; else hi = mid;
    }
    return lo;
}

__global__ __launch_bounds__(256) void seg_mean_embed_bsearch_kernel(
    const int* __restrict__ tokens,
    const int* __restrict__ seg_ids,
    const float* __restrict__ emb,
    const float* __restrict__ pos,
    float* __restrict__ out,
    int T)
{
    const int seg = blockIdx.x;
    const int lo = lower_bound_dev(seg_ids, T, seg);
    const int hi = lower_bound_dev(seg_ids, T, seg + 1);
    const int d = threadIdx.x * 4;

    f32x4 acc = (f32x4)(0.f);
    for (int t = lo; t < hi; ++t) {
        const int tok = tokens[t];
        acc += *reinterpret_cast<const f32x4*>(emb + (size_t)tok * DD + d);
    }
    const int cnt = hi - lo;
    const float inv = (cnt > 0) ? (1.0f / (float)cnt) : 0.0f;
    const int s = seg & (SS - 1);
    const f32x4 p = *reinterpret_cast<const f32x4*>(pos + (size_t)s * DD + d);
    f32x4 o = acc * inv + p;
    *reinterpret_cast<f32x4*>(out + (size_t)seg * DD + d) = o;
}

extern "C" void kernel_launch(void* const* d_in, const int* in_sizes, int n_in,
                              void* d_out, int out_size, void* d_ws, size_t ws_size,
                              hipStream_t stream) {
    const int*   tokens  = (const int*)d_in[0];
    const int*   seg_ids = (const int*)d_in[1];
    const float* emb     = (const float*)d_in[2];
    const float* pos     = (const float*)d_in[3];
    float*       out     = (float*)d_out;
    const int T = in_sizes[0];

    const size_t need = (size_t)(NSEG + 1) * sizeof(int);
    if (ws_size >= need) {
        int* seg_start = (int*)d_ws;
        fill_bounds_kernel<<<(T + 255) / 256, 256, 0, stream>>>(seg_ids, seg_start, T);
        seg_mean_2s_kernel<<<GRID, THREADS, 0, stream>>>(tokens, seg_start, emb, pos, out);
    } else {
        seg_mean_embed_bsearch_kernel<<<NSEG, 256, 0, stream>>>(tokens, seg_ids, emb, pos, out, T);
    }
}